// Round 1
// baseline (521.344 us; speedup 1.0000x reference)
//
#include <hip/hip_runtime.h>
#include <math.h>

constexpr int IN_DIM = 512;
constexpr int HID = 64;
constexpr int OUTD = 40;

// ---------------- GEMM1: h1[N,64] = x[N,512] @ W1[512,64] (fp32) ----------------
// 64x64 block tile, 256 threads, 4x4 microtile, BK=32.
__global__ __launch_bounds__(256) void gemm1_kernel(const float* __restrict__ x,
                                                    const float* __restrict__ W1,
                                                    float* __restrict__ h1, int N) {
    __shared__ float As[32][68];  // [k][row], padded row (272B, 16B aligned)
    __shared__ float Bs[32][64];  // [k][col]
    const int tid = threadIdx.x;
    const int tx = tid & 15;   // col group (4 cols)
    const int ty = tid >> 4;   // row group (4 rows)
    const int row0 = blockIdx.x * 64;
    float acc[4][4] = {};

    for (int k0 = 0; k0 < IN_DIM; k0 += 32) {
        // Load A tile: 64 rows x 32 k = 512 float4, 2 per thread. Transpose into As[k][row].
#pragma unroll
        for (int t = 0; t < 2; ++t) {
            int q = tid + t * 256;
            int r = q >> 3;            // tile row
            int kc = (q & 7) << 2;     // k offset (float4)
            float4 v = make_float4(0.f, 0.f, 0.f, 0.f);
            int grow = row0 + r;
            if (grow < N) v = *(const float4*)&x[(size_t)grow * IN_DIM + k0 + kc];
            As[kc + 0][r] = v.x;
            As[kc + 1][r] = v.y;
            As[kc + 2][r] = v.z;
            As[kc + 3][r] = v.w;
        }
        // Load B tile: 32 k x 64 cols = 512 float4, 2 per thread.
#pragma unroll
        for (int t = 0; t < 2; ++t) {
            int q = tid + t * 256;
            int kr = q >> 4;
            int nc = (q & 15) << 2;
            *(float4*)&Bs[kr][nc] = *(const float4*)&W1[(size_t)(k0 + kr) * HID + nc];
        }
        __syncthreads();
#pragma unroll
        for (int kk = 0; kk < 32; ++kk) {
            float4 a = *(const float4*)&As[kk][ty * 4];
            float4 b = *(const float4*)&Bs[kk][tx * 4];
            float av[4] = {a.x, a.y, a.z, a.w};
            float bv[4] = {b.x, b.y, b.z, b.w};
#pragma unroll
            for (int i = 0; i < 4; ++i)
#pragma unroll
                for (int j = 0; j < 4; ++j) acc[i][j] += av[i] * bv[j];
        }
        __syncthreads();
    }
#pragma unroll
    for (int i = 0; i < 4; ++i) {
        int r = row0 + ty * 4 + i;
        if (r < N) {
            *(float4*)&h1[(size_t)r * HID + tx * 4] =
                make_float4(acc[i][0], acc[i][1], acc[i][2], acc[i][3]);
        }
    }
}

// ---------------- Scatter-add 1: agg1[dst[e]] += h1[src[e]], 64 feats ----------------
__global__ __launch_bounds__(256) void scatter1_kernel(const float* __restrict__ h1,
                                                       const int* __restrict__ src,
                                                       const int* __restrict__ dst,
                                                       float* __restrict__ agg1, int E) {
    long tid = (long)blockIdx.x * 256 + threadIdx.x;
    int e = (int)(tid >> 6);
    int f = (int)(tid & 63);
    if (e < E) {
        float v = h1[(size_t)src[e] * HID + f];
        atomicAdd(&agg1[(size_t)dst[e] * HID + f], v);
    }
}

// ---------------- GEMM2 (+fused ReLU on input): h2[N,40] = relu(agg1)[N,64] @ W2[64,40]
// 5 threads per row, 8 cols each; W2 staged in LDS.
__global__ __launch_bounds__(256) void gemm2_kernel(const float* __restrict__ agg1,
                                                    const float* __restrict__ W2,
                                                    float* __restrict__ h2, int N) {
    __shared__ float W2s[HID * OUTD];
    for (int i = threadIdx.x; i < HID * OUTD; i += 256) W2s[i] = W2[i];
    __syncthreads();
    int tid = blockIdx.x * 256 + threadIdx.x;
    if (tid >= N * 5) return;
    int row = tid / 5;
    int c0 = (tid - row * 5) * 8;
    const float* arow = &agg1[(size_t)row * HID];
    float acc[8] = {};
#pragma unroll
    for (int k4 = 0; k4 < 16; ++k4) {
        float4 a4 = *(const float4*)&arow[k4 * 4];
        float av[4] = {fmaxf(a4.x, 0.f), fmaxf(a4.y, 0.f), fmaxf(a4.z, 0.f), fmaxf(a4.w, 0.f)};
#pragma unroll
        for (int j = 0; j < 4; ++j) {
            int k = k4 * 4 + j;
            float a = av[j];
            float4 w0 = *(const float4*)&W2s[k * OUTD + c0];
            float4 w1 = *(const float4*)&W2s[k * OUTD + c0 + 4];
            acc[0] += a * w0.x; acc[1] += a * w0.y; acc[2] += a * w0.z; acc[3] += a * w0.w;
            acc[4] += a * w1.x; acc[5] += a * w1.y; acc[6] += a * w1.z; acc[7] += a * w1.w;
        }
    }
    float4* o = (float4*)&h2[(size_t)row * OUTD + c0];
    o[0] = make_float4(acc[0], acc[1], acc[2], acc[3]);
    o[1] = make_float4(acc[4], acc[5], acc[6], acc[7]);
}

// ---------------- Scatter-add 2: agg2[dst[e]] += h2[src[e]], 40 feats ----------------
__global__ __launch_bounds__(256) void scatter2_kernel(const float* __restrict__ h2,
                                                       const int* __restrict__ src,
                                                       const int* __restrict__ dst,
                                                       float* __restrict__ agg2, int E) {
    long tid = (long)blockIdx.x * 256 + threadIdx.x;
    long total = (long)E * OUTD;
    if (tid >= total) return;
    int e = (int)(tid / OUTD);
    int f = (int)(tid - (long)e * OUTD);
    float v = h2[(size_t)src[e] * OUTD + f];
    atomicAdd(&agg2[(size_t)dst[e] * OUTD + f], v);
}

// ---------------- log_softmax over 40 cols, one wave per row ----------------
__global__ __launch_bounds__(256) void lsm_kernel(const float* __restrict__ agg2,
                                                  float* __restrict__ out, int N) {
    int wave = (blockIdx.x * 256 + threadIdx.x) >> 6;
    int lane = threadIdx.x & 63;
    if (wave >= N) return;
    float v = (lane < OUTD) ? agg2[(size_t)wave * OUTD + lane] : -INFINITY;
    float m = v;
#pragma unroll
    for (int o = 32; o; o >>= 1) m = fmaxf(m, __shfl_xor(m, o, 64));
    float ex = (lane < OUTD) ? expf(v - m) : 0.f;
    float s = ex;
#pragma unroll
    for (int o = 32; o; o >>= 1) s += __shfl_xor(s, o, 64);
    if (lane < OUTD) out[(size_t)wave * OUTD + lane] = v - m - logf(s);
}

extern "C" void kernel_launch(void* const* d_in, const int* in_sizes, int n_in,
                              void* d_out, int out_size, void* d_ws, size_t ws_size,
                              hipStream_t stream) {
    const float* x  = (const float*)d_in[0];
    const int*  src = (const int*)d_in[1];
    const int*  dst = (const int*)d_in[2];
    const float* W1 = (const float*)d_in[3];
    const float* W2 = (const float*)d_in[4];
    float* out = (float*)d_out;

    const int N = in_sizes[0] / IN_DIM;   // 50000
    const int E = in_sizes[1];            // 800000

    float* h1   = (float*)d_ws;                  // N*64
    float* agg1 = h1 + (size_t)N * HID;          // N*64
    float* h2   = agg1 + (size_t)N * HID;        // N*40
    float* agg2 = h2 + (size_t)N * OUTD;         // N*40

    hipMemsetAsync(agg1, 0, (size_t)N * HID * sizeof(float), stream);
    hipMemsetAsync(agg2, 0, (size_t)N * OUTD * sizeof(float), stream);

    // Layer 1
    gemm1_kernel<<<(N + 63) / 64, 256, 0, stream>>>(x, W1, h1, N);
    {
        long threads = (long)E * 64;
        scatter1_kernel<<<(int)((threads + 255) / 256), 256, 0, stream>>>(h1, src, dst, agg1, E);
    }
    // Layer 2 (ReLU fused into gemm2 input)
    gemm2_kernel<<<(N * 5 + 255) / 256, 256, 0, stream>>>(agg1, W2, h2, N);
    {
        long threads = (long)E * OUTD;
        scatter2_kernel<<<(int)((threads + 255) / 256), 256, 0, stream>>>(h2, src, dst, agg2, E);
    }
    // Output
    lsm_kernel<<<(N + 3) / 4, 256, 0, stream>>>(agg2, out, N);
}

// Round 2
// 472.612 us; speedup vs baseline: 1.1031x; 1.1031x over previous
//
#include <hip/hip_runtime.h>
#include <math.h>

constexpr int IN_DIM = 512;
constexpr int HID = 64;
constexpr int OUTD = 40;

// ---------------- GEMM1: h1[N,64] = x[N,512] @ W1[512,64] (fp32) ----------------
__global__ __launch_bounds__(256) void gemm1_kernel(const float* __restrict__ x,
                                                    const float* __restrict__ W1,
                                                    float* __restrict__ h1, int N) {
    __shared__ float As[32][68];
    __shared__ float Bs[32][64];
    const int tid = threadIdx.x;
    const int tx = tid & 15;
    const int ty = tid >> 4;
    const int row0 = blockIdx.x * 64;
    float acc[4][4] = {};

    for (int k0 = 0; k0 < IN_DIM; k0 += 32) {
#pragma unroll
        for (int t = 0; t < 2; ++t) {
            int q = tid + t * 256;
            int r = q >> 3;
            int kc = (q & 7) << 2;
            float4 v = make_float4(0.f, 0.f, 0.f, 0.f);
            int grow = row0 + r;
            if (grow < N) v = *(const float4*)&x[(size_t)grow * IN_DIM + k0 + kc];
            As[kc + 0][r] = v.x;
            As[kc + 1][r] = v.y;
            As[kc + 2][r] = v.z;
            As[kc + 3][r] = v.w;
        }
#pragma unroll
        for (int t = 0; t < 2; ++t) {
            int q = tid + t * 256;
            int kr = q >> 4;
            int nc = (q & 15) << 2;
            *(float4*)&Bs[kr][nc] = *(const float4*)&W1[(size_t)(k0 + kr) * HID + nc];
        }
        __syncthreads();
#pragma unroll
        for (int kk = 0; kk < 32; ++kk) {
            float4 a = *(const float4*)&As[kk][ty * 4];
            float4 b = *(const float4*)&Bs[kk][tx * 4];
            float av[4] = {a.x, a.y, a.z, a.w};
            float bv[4] = {b.x, b.y, b.z, b.w};
#pragma unroll
            for (int i = 0; i < 4; ++i)
#pragma unroll
                for (int j = 0; j < 4; ++j) acc[i][j] += av[i] * bv[j];
        }
        __syncthreads();
    }
#pragma unroll
    for (int i = 0; i < 4; ++i) {
        int r = row0 + ty * 4 + i;
        if (r < N) {
            *(float4*)&h1[(size_t)r * HID + tx * 4] =
                make_float4(acc[i][0], acc[i][1], acc[i][2], acc[i][3]);
        }
    }
}

// ---------------- CSR build ----------------
__global__ __launch_bounds__(256) void deg_kernel(const int* __restrict__ dst,
                                                  int* __restrict__ deg, int E) {
    int e = blockIdx.x * 256 + threadIdx.x;
    if (e < E) atomicAdd(&deg[dst[e]], 1);
}

// Single-block exclusive scan over N (<= 1024*per) elements; writes rowptr[N]=E.
__global__ __launch_bounds__(1024) void scan_kernel(const int* __restrict__ deg,
                                                    int* __restrict__ rowptr,
                                                    int* __restrict__ cursor, int N, int E) {
    __shared__ int sums[1024];
    const int tid = threadIdx.x;
    const int per = (N + 1023) >> 10;
    const int start = tid * per;
    int s = 0;
    for (int i = 0; i < per; ++i) {
        int idx = start + i;
        if (idx < N) s += deg[idx];
    }
    sums[tid] = s;
    __syncthreads();
    for (int off = 1; off < 1024; off <<= 1) {
        int t = 0;
        if (tid >= off) t = sums[tid - off];
        __syncthreads();
        sums[tid] += t;
        __syncthreads();
    }
    int run = sums[tid] - s;  // exclusive prefix of this thread's chunk
    for (int i = 0; i < per; ++i) {
        int idx = start + i;
        if (idx < N) {
            rowptr[idx] = run;
            cursor[idx] = run;
            run += deg[idx];
        }
    }
    if (tid == 1023) rowptr[N] = E;
}

__global__ __launch_bounds__(256) void fill_kernel(const int* __restrict__ src,
                                                   const int* __restrict__ dst,
                                                   int* __restrict__ cursor,
                                                   int* __restrict__ srcs, int E) {
    int e = blockIdx.x * 256 + threadIdx.x;
    if (e < E) {
        int pos = atomicAdd(&cursor[dst[e]], 1);
        srcs[pos] = src[e];
    }
}

// ---------------- Gather-agg 1: agg1[i] = sum_{e in in(i)} h1[srcs[e]], 64 feats ----------------
__global__ __launch_bounds__(256) void agg1_kernel(const float* __restrict__ h1,
                                                   const int* __restrict__ rowptr,
                                                   const int* __restrict__ srcs,
                                                   float* __restrict__ agg1, int N) {
    int node = (blockIdx.x * 256 + threadIdx.x) >> 6;
    int lane = threadIdx.x & 63;
    if (node >= N) return;
    int b = rowptr[node], e = rowptr[node + 1];
    float acc = 0.f;
    int j = b;
    for (; j + 4 <= e; j += 4) {
        int s0 = srcs[j], s1 = srcs[j + 1], s2 = srcs[j + 2], s3 = srcs[j + 3];
        float v0 = h1[(size_t)s0 * HID + lane];
        float v1 = h1[(size_t)s1 * HID + lane];
        float v2 = h1[(size_t)s2 * HID + lane];
        float v3 = h1[(size_t)s3 * HID + lane];
        acc += v0 + v1 + v2 + v3;
    }
    for (; j < e; ++j) acc += h1[(size_t)srcs[j] * HID + lane];
    agg1[(size_t)node * HID + lane] = acc;
}

// ---------------- GEMM2 (+fused ReLU on input): h2[N,40] = relu(agg1)[N,64] @ W2[64,40]
__global__ __launch_bounds__(256) void gemm2_kernel(const float* __restrict__ agg1,
                                                    const float* __restrict__ W2,
                                                    float* __restrict__ h2, int N) {
    __shared__ float W2s[HID * OUTD];
    for (int i = threadIdx.x; i < HID * OUTD; i += 256) W2s[i] = W2[i];
    __syncthreads();
    int tid = blockIdx.x * 256 + threadIdx.x;
    if (tid >= N * 5) return;
    int row = tid / 5;
    int c0 = (tid - row * 5) * 8;
    const float* arow = &agg1[(size_t)row * HID];
    float acc[8] = {};
#pragma unroll
    for (int k4 = 0; k4 < 16; ++k4) {
        float4 a4 = *(const float4*)&arow[k4 * 4];
        float av[4] = {fmaxf(a4.x, 0.f), fmaxf(a4.y, 0.f), fmaxf(a4.z, 0.f), fmaxf(a4.w, 0.f)};
#pragma unroll
        for (int j = 0; j < 4; ++j) {
            int k = k4 * 4 + j;
            float a = av[j];
            float4 w0 = *(const float4*)&W2s[k * OUTD + c0];
            float4 w1 = *(const float4*)&W2s[k * OUTD + c0 + 4];
            acc[0] += a * w0.x; acc[1] += a * w0.y; acc[2] += a * w0.z; acc[3] += a * w0.w;
            acc[4] += a * w1.x; acc[5] += a * w1.y; acc[6] += a * w1.z; acc[7] += a * w1.w;
        }
    }
    float4* o = (float4*)&h2[(size_t)row * OUTD + c0];
    o[0] = make_float4(acc[0], acc[1], acc[2], acc[3]);
    o[1] = make_float4(acc[4], acc[5], acc[6], acc[7]);
}

// ---------------- Gather-agg 2 + log_softmax fused: one wave per node ----------------
__global__ __launch_bounds__(256) void agg2_lsm_kernel(const float* __restrict__ h2,
                                                       const int* __restrict__ rowptr,
                                                       const int* __restrict__ srcs,
                                                       float* __restrict__ out, int N) {
    int node = (blockIdx.x * 256 + threadIdx.x) >> 6;
    int lane = threadIdx.x & 63;
    if (node >= N) return;
    int b = rowptr[node], e = rowptr[node + 1];
    const bool act = lane < OUTD;
    float acc = 0.f;
    int j = b;
    for (; j + 4 <= e; j += 4) {
        int s0 = srcs[j], s1 = srcs[j + 1], s2 = srcs[j + 2], s3 = srcs[j + 3];
        if (act) {
            float v0 = h2[(size_t)s0 * OUTD + lane];
            float v1 = h2[(size_t)s1 * OUTD + lane];
            float v2 = h2[(size_t)s2 * OUTD + lane];
            float v3 = h2[(size_t)s3 * OUTD + lane];
            acc += v0 + v1 + v2 + v3;
        }
    }
    for (; j < e; ++j)
        if (act) acc += h2[(size_t)srcs[j] * OUTD + lane];

    float v = act ? acc : -INFINITY;
    float m = v;
#pragma unroll
    for (int o = 32; o; o >>= 1) m = fmaxf(m, __shfl_xor(m, o, 64));
    float ex = act ? expf(v - m) : 0.f;
    float s = ex;
#pragma unroll
    for (int o = 32; o; o >>= 1) s += __shfl_xor(s, o, 64);
    if (act) out[(size_t)node * OUTD + lane] = v - m - logf(s);
}

extern "C" void kernel_launch(void* const* d_in, const int* in_sizes, int n_in,
                              void* d_out, int out_size, void* d_ws, size_t ws_size,
                              hipStream_t stream) {
    const float* x  = (const float*)d_in[0];
    const int*  src = (const int*)d_in[1];
    const int*  dst = (const int*)d_in[2];
    const float* W1 = (const float*)d_in[3];
    const float* W2 = (const float*)d_in[4];
    float* out = (float*)d_out;

    const int N = in_sizes[0] / IN_DIM;   // 50000
    const int E = in_sizes[1];            // 800000

    // Workspace carve-up (all 4-byte types; base assumed 16B-aligned)
    float* h1     = (float*)d_ws;                    // N*64
    float* agg1   = h1 + (size_t)N * HID;            // N*64
    float* h2     = agg1 + (size_t)N * HID;          // N*40
    int*   deg    = (int*)(h2 + (size_t)N * OUTD);   // N
    int*   rowptr = deg + N;                         // N+1
    int*   cursor = rowptr + N + 1;                  // N
    int*   srcs   = cursor + N;                      // E

    hipMemsetAsync(deg, 0, (size_t)N * sizeof(int), stream);

    // GEMM1 (independent of CSR build)
    gemm1_kernel<<<(N + 63) / 64, 256, 0, stream>>>(x, W1, h1, N);

    // CSR build: deg -> rowptr/cursor -> srcs (sorted by dst)
    deg_kernel<<<(E + 255) / 256, 256, 0, stream>>>(dst, deg, E);
    scan_kernel<<<1, 1024, 0, stream>>>(deg, rowptr, cursor, N, E);
    fill_kernel<<<(E + 255) / 256, 256, 0, stream>>>(src, dst, cursor, srcs, E);

    // Layer 1 aggregation (gather)
    agg1_kernel<<<(N * 64 + 255) / 256, 256, 0, stream>>>(h1, rowptr, srcs, agg1, N);

    // Layer 2: relu+gemm, then fused gather+log_softmax
    gemm2_kernel<<<(N * 5 + 255) / 256, 256, 0, stream>>>(agg1, W2, h2, N);
    agg2_lsm_kernel<<<(N * 64 + 255) / 256, 256, 0, stream>>>(h2, rowptr, srcs, out, N);
}

// Round 3
// 357.328 us; speedup vs baseline: 1.4590x; 1.3226x over previous
//
#include <hip/hip_runtime.h>
#include <math.h>

constexpr int IN_DIM = 512;
constexpr int HID = 64;
constexpr int OUTD = 40;
constexpr int SCAN_CHUNK = 1024;  // elements per block in the 3-phase scan

// ---------------- GEMM1: h1[N,64] = x[N,512] @ W1[512,64] (fp32) ----------------
__global__ __launch_bounds__(256) void gemm1_kernel(const float* __restrict__ x,
                                                    const float* __restrict__ W1,
                                                    float* __restrict__ h1, int N) {
    __shared__ float As[32][68];
    __shared__ float Bs[32][64];
    const int tid = threadIdx.x;
    const int tx = tid & 15;
    const int ty = tid >> 4;
    const int row0 = blockIdx.x * 64;
    float acc[4][4] = {};

    for (int k0 = 0; k0 < IN_DIM; k0 += 32) {
#pragma unroll
        for (int t = 0; t < 2; ++t) {
            int q = tid + t * 256;
            int r = q >> 3;
            int kc = (q & 7) << 2;
            float4 v = make_float4(0.f, 0.f, 0.f, 0.f);
            int grow = row0 + r;
            if (grow < N) v = *(const float4*)&x[(size_t)grow * IN_DIM + k0 + kc];
            As[kc + 0][r] = v.x;
            As[kc + 1][r] = v.y;
            As[kc + 2][r] = v.z;
            As[kc + 3][r] = v.w;
        }
#pragma unroll
        for (int t = 0; t < 2; ++t) {
            int q = tid + t * 256;
            int kr = q >> 4;
            int nc = (q & 15) << 2;
            *(float4*)&Bs[kr][nc] = *(const float4*)&W1[(size_t)(k0 + kr) * HID + nc];
        }
        __syncthreads();
#pragma unroll
        for (int kk = 0; kk < 32; ++kk) {
            float4 a = *(const float4*)&As[kk][ty * 4];
            float4 b = *(const float4*)&Bs[kk][tx * 4];
            float av[4] = {a.x, a.y, a.z, a.w};
            float bv[4] = {b.x, b.y, b.z, b.w};
#pragma unroll
            for (int i = 0; i < 4; ++i)
#pragma unroll
                for (int j = 0; j < 4; ++j) acc[i][j] += av[i] * bv[j];
        }
        __syncthreads();
    }
#pragma unroll
    for (int i = 0; i < 4; ++i) {
        int r = row0 + ty * 4 + i;
        if (r < N) {
            *(float4*)&h1[(size_t)r * HID + tx * 4] =
                make_float4(acc[i][0], acc[i][1], acc[i][2], acc[i][3]);
        }
    }
}

// ---------------- CSR build ----------------
__global__ __launch_bounds__(256) void deg_kernel(const int* __restrict__ dst,
                                                  int* __restrict__ deg, int E) {
    int e = blockIdx.x * 256 + threadIdx.x;
    if (e < E) atomicAdd(&deg[dst[e]], 1);
}

// 3-phase scan. Phase A: per-block sums (256 thr x 4 elems).
__global__ __launch_bounds__(256) void scanA_kernel(const int* __restrict__ deg,
                                                    int* __restrict__ blockSums, int N) {
    __shared__ int sm[256];
    const int t = threadIdx.x;
    const int base = blockIdx.x * SCAN_CHUNK + t * 4;
    int s = 0;
    if (base + 3 < N) {
        int4 v = *(const int4*)&deg[base];
        s = v.x + v.y + v.z + v.w;
    } else {
#pragma unroll
        for (int i = 0; i < 4; ++i)
            if (base + i < N) s += deg[base + i];
    }
    sm[t] = s;
    __syncthreads();
    for (int off = 128; off; off >>= 1) {
        if (t < off) sm[t] += sm[t + off];
        __syncthreads();
    }
    if (t == 0) blockSums[blockIdx.x] = sm[0];
}

// Phase B: exclusive scan of block sums (nb <= 256), single block.
__global__ __launch_bounds__(256) void scanB_kernel(int* __restrict__ blockSums, int nb) {
    __shared__ int sm[256];
    const int t = threadIdx.x;
    int v = (t < nb) ? blockSums[t] : 0;
    sm[t] = v;
    __syncthreads();
    for (int off = 1; off < 256; off <<= 1) {
        int u = (t >= off) ? sm[t - off] : 0;
        __syncthreads();
        sm[t] += u;
        __syncthreads();
    }
    if (t < nb) blockSums[t] = sm[t] - v;  // exclusive
}

// Phase C: per-block exclusive scan + offset; writes rowptr and cursor.
__global__ __launch_bounds__(256) void scanC_kernel(const int* __restrict__ deg,
                                                    const int* __restrict__ blockSums,
                                                    int* __restrict__ rowptr,
                                                    int* __restrict__ cursor, int N, int E) {
    __shared__ int sm[256];
    const int t = threadIdx.x;
    const int base = blockIdx.x * SCAN_CHUNK + t * 4;
    int v[4] = {0, 0, 0, 0};
    if (base + 3 < N) {
        int4 q = *(const int4*)&deg[base];
        v[0] = q.x; v[1] = q.y; v[2] = q.z; v[3] = q.w;
    } else {
#pragma unroll
        for (int i = 0; i < 4; ++i)
            if (base + i < N) v[i] = deg[base + i];
    }
    int s = v[0] + v[1] + v[2] + v[3];
    sm[t] = s;
    __syncthreads();
    for (int off = 1; off < 256; off <<= 1) {
        int u = (t >= off) ? sm[t - off] : 0;
        __syncthreads();
        sm[t] += u;
        __syncthreads();
    }
    int run = blockSums[blockIdx.x] + sm[t] - s;
#pragma unroll
    for (int i = 0; i < 4; ++i) {
        int idx = base + i;
        if (idx < N) {
            rowptr[idx] = run;
            cursor[idx] = run;
            run += v[i];
        }
    }
    if (blockIdx.x == 0 && t == 0) rowptr[N] = E;
}

__global__ __launch_bounds__(256) void fill_kernel(const int* __restrict__ src,
                                                   const int* __restrict__ dst,
                                                   int* __restrict__ cursor,
                                                   int* __restrict__ srcs, int E) {
    int e = blockIdx.x * 256 + threadIdx.x;
    if (e < E) {
        int pos = atomicAdd(&cursor[dst[e]], 1);
        srcs[pos] = src[e];
    }
}

// ---------------- Gather-agg 1: agg1[i] = sum_{e in in(i)} h1[srcs[e]], 64 feats ----------------
__global__ __launch_bounds__(256) void agg1_kernel(const float* __restrict__ h1,
                                                   const int* __restrict__ rowptr,
                                                   const int* __restrict__ srcs,
                                                   float* __restrict__ agg1, int N) {
    int node = (blockIdx.x * 256 + threadIdx.x) >> 6;
    int lane = threadIdx.x & 63;
    if (node >= N) return;
    int b = rowptr[node], e = rowptr[node + 1];
    float acc = 0.f;
    int j = b;
    for (; j + 4 <= e; j += 4) {
        int s0 = srcs[j], s1 = srcs[j + 1], s2 = srcs[j + 2], s3 = srcs[j + 3];
        float v0 = h1[(size_t)s0 * HID + lane];
        float v1 = h1[(size_t)s1 * HID + lane];
        float v2 = h1[(size_t)s2 * HID + lane];
        float v3 = h1[(size_t)s3 * HID + lane];
        acc += v0 + v1 + v2 + v3;
    }
    for (; j < e; ++j) acc += h1[(size_t)srcs[j] * HID + lane];
    agg1[(size_t)node * HID + lane] = acc;
}

// ---------------- GEMM2 (+fused ReLU on input): h2[N,40] = relu(agg1)[N,64] @ W2[64,40]
__global__ __launch_bounds__(256) void gemm2_kernel(const float* __restrict__ agg1,
                                                    const float* __restrict__ W2,
                                                    float* __restrict__ h2, int N) {
    __shared__ float W2s[HID * OUTD];
    for (int i = threadIdx.x; i < HID * OUTD; i += 256) W2s[i] = W2[i];
    __syncthreads();
    int tid = blockIdx.x * 256 + threadIdx.x;
    if (tid >= N * 5) return;
    int row = tid / 5;
    int c0 = (tid - row * 5) * 8;
    const float* arow = &agg1[(size_t)row * HID];
    float acc[8] = {};
#pragma unroll
    for (int k4 = 0; k4 < 16; ++k4) {
        float4 a4 = *(const float4*)&arow[k4 * 4];
        float av[4] = {fmaxf(a4.x, 0.f), fmaxf(a4.y, 0.f), fmaxf(a4.z, 0.f), fmaxf(a4.w, 0.f)};
#pragma unroll
        for (int j = 0; j < 4; ++j) {
            int k = k4 * 4 + j;
            float a = av[j];
            float4 w0 = *(const float4*)&W2s[k * OUTD + c0];
            float4 w1 = *(const float4*)&W2s[k * OUTD + c0 + 4];
            acc[0] += a * w0.x; acc[1] += a * w0.y; acc[2] += a * w0.z; acc[3] += a * w0.w;
            acc[4] += a * w1.x; acc[5] += a * w1.y; acc[6] += a * w1.z; acc[7] += a * w1.w;
        }
    }
    float4* o = (float4*)&h2[(size_t)row * OUTD + c0];
    o[0] = make_float4(acc[0], acc[1], acc[2], acc[3]);
    o[1] = make_float4(acc[4], acc[5], acc[6], acc[7]);
}

// ---------------- Gather-agg 2 + log_softmax fused: one wave per node ----------------
__global__ __launch_bounds__(256) void agg2_lsm_kernel(const float* __restrict__ h2,
                                                       const int* __restrict__ rowptr,
                                                       const int* __restrict__ srcs,
                                                       float* __restrict__ out, int N) {
    int node = (blockIdx.x * 256 + threadIdx.x) >> 6;
    int lane = threadIdx.x & 63;
    if (node >= N) return;
    int b = rowptr[node], e = rowptr[node + 1];
    const bool act = lane < OUTD;
    float acc = 0.f;
    int j = b;
    for (; j + 4 <= e; j += 4) {
        int s0 = srcs[j], s1 = srcs[j + 1], s2 = srcs[j + 2], s3 = srcs[j + 3];
        if (act) {
            float v0 = h2[(size_t)s0 * OUTD + lane];
            float v1 = h2[(size_t)s1 * OUTD + lane];
            float v2 = h2[(size_t)s2 * OUTD + lane];
            float v3 = h2[(size_t)s3 * OUTD + lane];
            acc += v0 + v1 + v2 + v3;
        }
    }
    for (; j < e; ++j)
        if (act) acc += h2[(size_t)srcs[j] * OUTD + lane];

    float v = act ? acc : -INFINITY;
    float m = v;
#pragma unroll
    for (int o = 32; o; o >>= 1) m = fmaxf(m, __shfl_xor(m, o, 64));
    float ex = act ? expf(v - m) : 0.f;
    float s = ex;
#pragma unroll
    for (int o = 32; o; o >>= 1) s += __shfl_xor(s, o, 64);
    if (act) out[(size_t)node * OUTD + lane] = v - m - logf(s);
}

extern "C" void kernel_launch(void* const* d_in, const int* in_sizes, int n_in,
                              void* d_out, int out_size, void* d_ws, size_t ws_size,
                              hipStream_t stream) {
    const float* x  = (const float*)d_in[0];
    const int*  src = (const int*)d_in[1];
    const int*  dst = (const int*)d_in[2];
    const float* W1 = (const float*)d_in[3];
    const float* W2 = (const float*)d_in[4];
    float* out = (float*)d_out;

    const int N = in_sizes[0] / IN_DIM;   // 50000
    const int E = in_sizes[1];            // 800000

    // Workspace carve-up (all 4-byte types; base assumed 16B-aligned)
    float* h1        = (float*)d_ws;                     // N*64
    float* agg1      = h1 + (size_t)N * HID;             // N*64
    float* h2        = agg1 + (size_t)N * HID;           // N*40
    int*   deg       = (int*)(h2 + (size_t)N * OUTD);    // N
    int*   rowptr    = deg + N;                          // N+1
    int*   cursor    = rowptr + N + 1;                   // N
    int*   blockSums = cursor + N;                       // <=256
    int*   srcs      = blockSums + 256;                  // E

    const int nScanBlocks = (N + SCAN_CHUNK - 1) / SCAN_CHUNK;  // 49 for N=50000

    hipMemsetAsync(deg, 0, (size_t)N * sizeof(int), stream);

    // GEMM1 (independent of CSR build)
    gemm1_kernel<<<(N + 63) / 64, 256, 0, stream>>>(x, W1, h1, N);

    // CSR build: deg -> 3-phase scan -> fill (srcs sorted by dst)
    deg_kernel<<<(E + 255) / 256, 256, 0, stream>>>(dst, deg, E);
    scanA_kernel<<<nScanBlocks, 256, 0, stream>>>(deg, blockSums, N);
    scanB_kernel<<<1, 256, 0, stream>>>(blockSums, nScanBlocks);
    scanC_kernel<<<nScanBlocks, 256, 0, stream>>>(deg, blockSums, rowptr, cursor, N, E);
    fill_kernel<<<(E + 255) / 256, 256, 0, stream>>>(src, dst, cursor, srcs, E);

    // Layer 1 aggregation (gather)
    agg1_kernel<<<(N * 64 + 255) / 256, 256, 0, stream>>>(h1, rowptr, srcs, agg1, N);

    // Layer 2: relu+gemm, then fused gather+log_softmax
    gemm2_kernel<<<(N * 5 + 255) / 256, 256, 0, stream>>>(agg1, W2, h2, N);
    agg2_lsm_kernel<<<(N * 64 + 255) / 256, 256, 0, stream>>>(h2, rowptr, srcs, out, N);
}

// Round 4
// 347.968 us; speedup vs baseline: 1.4983x; 1.0269x over previous
//
#include <hip/hip_runtime.h>
#include <math.h>

constexpr int IN_DIM = 512;
constexpr int HID = 64;
constexpr int OUTD = 40;
constexpr int SCAN_CHUNK = 1024;

typedef __attribute__((ext_vector_type(8))) short bf16x8;
typedef __attribute__((ext_vector_type(4))) float floatx4;

__device__ __forceinline__ unsigned short f2bf(float f) {
    unsigned u = __float_as_uint(f);
    u += 0x7fff + ((u >> 16) & 1);  // round-to-nearest-even
    return (unsigned short)(u >> 16);
}

// ---------------- W1 transpose+convert: Wt[chunk c][n][k in chunk] bf16 ----------------
// Wt[((k>>5)*64 + n)*32 + (k&31)] = bf16(W1[k*64 + n]); 512x64 -> 64 KB.
__global__ __launch_bounds__(256) void w1t_kernel(const float* __restrict__ W1,
                                                  unsigned short* __restrict__ Wt) {
    int tid = blockIdx.x * 256 + threadIdx.x;  // 0..32767
    int k = tid >> 6;
    int n = tid & 63;
    Wt[(size_t)((k >> 5) * 64 + n) * 32 + (k & 31)] = f2bf(W1[tid]);
}

// ---------------- GEMM1 (bf16 MFMA, no LDS, no barriers) ----------------
// h1[N,64] = x[N,512] @ W1[512,64]. Block=256 (4 waves), 16 rows/wave.
__global__ __launch_bounds__(256, 4) void gemm1_kernel(const float* __restrict__ x,
                                                       const unsigned short* __restrict__ Wt,
                                                       float* __restrict__ h1, int N) {
    const int lane = threadIdx.x & 63;
    const int wave = threadIdx.x >> 6;
    const int lm = lane & 15;    // A: row-in-16 / B,D: col-in-16
    const int quad = lane >> 4;  // 0..3
    const int arow = blockIdx.x * 64 + wave * 16 + lm;
    const bool rowOK = arow < N;
    const float* xr = x + (size_t)arow * IN_DIM + quad * 8;
    const unsigned short* wb = Wt + lm * 32 + quad * 8;

    floatx4 acc0 = {0.f, 0.f, 0.f, 0.f};
    floatx4 acc1 = {0.f, 0.f, 0.f, 0.f};
    floatx4 acc2 = {0.f, 0.f, 0.f, 0.f};
    floatx4 acc3 = {0.f, 0.f, 0.f, 0.f};

#pragma unroll 2
    for (int c = 0; c < 16; ++c) {
        float4 a0 = make_float4(0.f, 0.f, 0.f, 0.f);
        float4 a1 = make_float4(0.f, 0.f, 0.f, 0.f);
        if (rowOK) {
            a0 = *(const float4*)(xr + c * 32);
            a1 = *(const float4*)(xr + c * 32 + 4);
        }
        bf16x8 af;
        af[0] = (short)f2bf(a0.x); af[1] = (short)f2bf(a0.y);
        af[2] = (short)f2bf(a0.z); af[3] = (short)f2bf(a0.w);
        af[4] = (short)f2bf(a1.x); af[5] = (short)f2bf(a1.y);
        af[6] = (short)f2bf(a1.z); af[7] = (short)f2bf(a1.w);

        const unsigned short* wc = wb + c * 2048;  // c*64*32
        bf16x8 b0 = *(const bf16x8*)(wc);          // cols 0..15
        bf16x8 b1 = *(const bf16x8*)(wc + 512);    // cols 16..31
        bf16x8 b2 = *(const bf16x8*)(wc + 1024);   // cols 32..47
        bf16x8 b3 = *(const bf16x8*)(wc + 1536);   // cols 48..63

        acc0 = __builtin_amdgcn_mfma_f32_16x16x32_bf16(af, b0, acc0, 0, 0, 0);
        acc1 = __builtin_amdgcn_mfma_f32_16x16x32_bf16(af, b1, acc1, 0, 0, 0);
        acc2 = __builtin_amdgcn_mfma_f32_16x16x32_bf16(af, b2, acc2, 0, 0, 0);
        acc3 = __builtin_amdgcn_mfma_f32_16x16x32_bf16(af, b3, acc3, 0, 0, 0);
    }

    // D layout: col = lane&15, row = quad*4 + reg (within this wave's 16-row block)
    const int r0 = blockIdx.x * 64 + wave * 16 + quad * 4;
#pragma unroll
    for (int reg = 0; reg < 4; ++reg) {
        int r = r0 + reg;
        if (r < N) {
            float* hr = h1 + (size_t)r * HID + lm;
            hr[0]  = acc0[reg];
            hr[16] = acc1[reg];
            hr[32] = acc2[reg];
            hr[48] = acc3[reg];
        }
    }
}

// ---------------- CSR build ----------------
__global__ __launch_bounds__(256) void deg_kernel(const int* __restrict__ dst,
                                                  int* __restrict__ deg, int E) {
    int e = blockIdx.x * 256 + threadIdx.x;
    if (e < E) atomicAdd(&deg[dst[e]], 1);
}

__global__ __launch_bounds__(256) void scanA_kernel(const int* __restrict__ deg,
                                                    int* __restrict__ blockSums, int N) {
    __shared__ int sm[256];
    const int t = threadIdx.x;
    const int base = blockIdx.x * SCAN_CHUNK + t * 4;
    int s = 0;
    if (base + 3 < N) {
        int4 v = *(const int4*)&deg[base];
        s = v.x + v.y + v.z + v.w;
    } else {
#pragma unroll
        for (int i = 0; i < 4; ++i)
            if (base + i < N) s += deg[base + i];
    }
    sm[t] = s;
    __syncthreads();
    for (int off = 128; off; off >>= 1) {
        if (t < off) sm[t] += sm[t + off];
        __syncthreads();
    }
    if (t == 0) blockSums[blockIdx.x] = sm[0];
}

__global__ __launch_bounds__(256) void scanB_kernel(int* __restrict__ blockSums, int nb) {
    __shared__ int sm[256];
    const int t = threadIdx.x;
    int v = (t < nb) ? blockSums[t] : 0;
    sm[t] = v;
    __syncthreads();
    for (int off = 1; off < 256; off <<= 1) {
        int u = (t >= off) ? sm[t - off] : 0;
        __syncthreads();
        sm[t] += u;
        __syncthreads();
    }
    if (t < nb) blockSums[t] = sm[t] - v;
}

__global__ __launch_bounds__(256) void scanC_kernel(const int* __restrict__ deg,
                                                    const int* __restrict__ blockSums,
                                                    int* __restrict__ rowptr,
                                                    int* __restrict__ cursor, int N, int E) {
    __shared__ int sm[256];
    const int t = threadIdx.x;
    const int base = blockIdx.x * SCAN_CHUNK + t * 4;
    int v[4] = {0, 0, 0, 0};
    if (base + 3 < N) {
        int4 q = *(const int4*)&deg[base];
        v[0] = q.x; v[1] = q.y; v[2] = q.z; v[3] = q.w;
    } else {
#pragma unroll
        for (int i = 0; i < 4; ++i)
            if (base + i < N) v[i] = deg[base + i];
    }
    int s = v[0] + v[1] + v[2] + v[3];
    sm[t] = s;
    __syncthreads();
    for (int off = 1; off < 256; off <<= 1) {
        int u = (t >= off) ? sm[t - off] : 0;
        __syncthreads();
        sm[t] += u;
        __syncthreads();
    }
    int run = blockSums[blockIdx.x] + sm[t] - s;
#pragma unroll
    for (int i = 0; i < 4; ++i) {
        int idx = base + i;
        if (idx < N) {
            rowptr[idx] = run;
            cursor[idx] = run;
            run += v[i];
        }
    }
    if (blockIdx.x == 0 && t == 0) rowptr[N] = E;
}

__global__ __launch_bounds__(256) void fill_kernel(const int* __restrict__ src,
                                                   const int* __restrict__ dst,
                                                   int* __restrict__ cursor,
                                                   int* __restrict__ srcs, int E) {
    int e = blockIdx.x * 256 + threadIdx.x;
    if (e < E) {
        int pos = atomicAdd(&cursor[dst[e]], 1);
        srcs[pos] = src[e];
    }
}

// ---------------- Gather-agg 1 ----------------
__global__ __launch_bounds__(256) void agg1_kernel(const float* __restrict__ h1,
                                                   const int* __restrict__ rowptr,
                                                   const int* __restrict__ srcs,
                                                   float* __restrict__ agg1, int N) {
    int node = (blockIdx.x * 256 + threadIdx.x) >> 6;
    int lane = threadIdx.x & 63;
    if (node >= N) return;
    int b = rowptr[node], e = rowptr[node + 1];
    float acc = 0.f;
    int j = b;
    for (; j + 4 <= e; j += 4) {
        int s0 = srcs[j], s1 = srcs[j + 1], s2 = srcs[j + 2], s3 = srcs[j + 3];
        float v0 = h1[(size_t)s0 * HID + lane];
        float v1 = h1[(size_t)s1 * HID + lane];
        float v2 = h1[(size_t)s2 * HID + lane];
        float v3 = h1[(size_t)s3 * HID + lane];
        acc += v0 + v1 + v2 + v3;
    }
    for (; j < e; ++j) acc += h1[(size_t)srcs[j] * HID + lane];
    agg1[(size_t)node * HID + lane] = acc;
}

// ---------------- GEMM2 (+fused ReLU on input) ----------------
__global__ __launch_bounds__(256) void gemm2_kernel(const float* __restrict__ agg1,
                                                    const float* __restrict__ W2,
                                                    float* __restrict__ h2, int N) {
    __shared__ float W2s[HID * OUTD];
    for (int i = threadIdx.x; i < HID * OUTD; i += 256) W2s[i] = W2[i];
    __syncthreads();
    int tid = blockIdx.x * 256 + threadIdx.x;
    if (tid >= N * 5) return;
    int row = tid / 5;
    int c0 = (tid - row * 5) * 8;
    const float* arow = &agg1[(size_t)row * HID];
    float acc[8] = {};
#pragma unroll
    for (int k4 = 0; k4 < 16; ++k4) {
        float4 a4 = *(const float4*)&arow[k4 * 4];
        float av[4] = {fmaxf(a4.x, 0.f), fmaxf(a4.y, 0.f), fmaxf(a4.z, 0.f), fmaxf(a4.w, 0.f)};
#pragma unroll
        for (int j = 0; j < 4; ++j) {
            int k = k4 * 4 + j;
            float a = av[j];
            float4 w0 = *(const float4*)&W2s[k * OUTD + c0];
            float4 w1 = *(const float4*)&W2s[k * OUTD + c0 + 4];
            acc[0] += a * w0.x; acc[1] += a * w0.y; acc[2] += a * w0.z; acc[3] += a * w0.w;
            acc[4] += a * w1.x; acc[5] += a * w1.y; acc[6] += a * w1.z; acc[7] += a * w1.w;
        }
    }
    float4* o = (float4*)&h2[(size_t)row * OUTD + c0];
    o[0] = make_float4(acc[0], acc[1], acc[2], acc[3]);
    o[1] = make_float4(acc[4], acc[5], acc[6], acc[7]);
}

// ---------------- Gather-agg 2 + log_softmax fused ----------------
__global__ __launch_bounds__(256) void agg2_lsm_kernel(const float* __restrict__ h2,
                                                       const int* __restrict__ rowptr,
                                                       const int* __restrict__ srcs,
                                                       float* __restrict__ out, int N) {
    int node = (blockIdx.x * 256 + threadIdx.x) >> 6;
    int lane = threadIdx.x & 63;
    if (node >= N) return;
    int b = rowptr[node], e = rowptr[node + 1];
    const bool act = lane < OUTD;
    float acc = 0.f;
    int j = b;
    for (; j + 4 <= e; j += 4) {
        int s0 = srcs[j], s1 = srcs[j + 1], s2 = srcs[j + 2], s3 = srcs[j + 3];
        if (act) {
            float v0 = h2[(size_t)s0 * OUTD + lane];
            float v1 = h2[(size_t)s1 * OUTD + lane];
            float v2 = h2[(size_t)s2 * OUTD + lane];
            float v3 = h2[(size_t)s3 * OUTD + lane];
            acc += v0 + v1 + v2 + v3;
        }
    }
    for (; j < e; ++j)
        if (act) acc += h2[(size_t)srcs[j] * OUTD + lane];

    float v = act ? acc : -INFINITY;
    float m = v;
#pragma unroll
    for (int o = 32; o; o >>= 1) m = fmaxf(m, __shfl_xor(m, o, 64));
    float ex = act ? expf(v - m) : 0.f;
    float s = ex;
#pragma unroll
    for (int o = 32; o; o >>= 1) s += __shfl_xor(s, o, 64);
    if (act) out[(size_t)node * OUTD + lane] = v - m - logf(s);
}

extern "C" void kernel_launch(void* const* d_in, const int* in_sizes, int n_in,
                              void* d_out, int out_size, void* d_ws, size_t ws_size,
                              hipStream_t stream) {
    const float* x  = (const float*)d_in[0];
    const int*  src = (const int*)d_in[1];
    const int*  dst = (const int*)d_in[2];
    const float* W1 = (const float*)d_in[3];
    const float* W2 = (const float*)d_in[4];
    float* out = (float*)d_out;

    const int N = in_sizes[0] / IN_DIM;   // 50000
    const int E = in_sizes[1];            // 800000

    // Workspace carve-up. Wt first to guarantee 16B alignment for b128 loads.
    unsigned short* Wt = (unsigned short*)d_ws;          // 512*64 bf16 = 64 KB
    float* h1        = (float*)d_ws + 16384;             // N*64
    float* agg1      = h1 + (size_t)N * HID;             // N*64
    float* h2        = agg1 + (size_t)N * HID;           // N*40
    int*   deg       = (int*)(h2 + (size_t)N * OUTD);    // N
    int*   rowptr    = deg + N;                          // N+1
    int*   cursor    = rowptr + N + 1;                   // N
    int*   blockSums = cursor + N;                       // <=256
    int*   srcs      = blockSums + 256;                  // E

    const int nScanBlocks = (N + SCAN_CHUNK - 1) / SCAN_CHUNK;

    hipMemsetAsync(deg, 0, (size_t)N * sizeof(int), stream);

    // W1 -> bf16 fragment layout, then MFMA GEMM1
    w1t_kernel<<<(IN_DIM * HID) / 256, 256, 0, stream>>>(W1, Wt);
    gemm1_kernel<<<(N + 63) / 64, 256, 0, stream>>>(x, Wt, h1, N);

    // CSR build: deg -> 3-phase scan -> fill (srcs sorted by dst)
    deg_kernel<<<(E + 255) / 256, 256, 0, stream>>>(dst, deg, E);
    scanA_kernel<<<nScanBlocks, 256, 0, stream>>>(deg, blockSums, N);
    scanB_kernel<<<1, 256, 0, stream>>>(blockSums, nScanBlocks);
    scanC_kernel<<<nScanBlocks, 256, 0, stream>>>(deg, blockSums, rowptr, cursor, N, E);
    fill_kernel<<<(E + 255) / 256, 256, 0, stream>>>(src, dst, cursor, srcs, E);

    // Layer 1 aggregation (gather)
    agg1_kernel<<<(N * 64 + 255) / 256, 256, 0, stream>>>(h1, rowptr, srcs, agg1, N);

    // Layer 2: relu+gemm, then fused gather+log_softmax
    gemm2_kernel<<<(N * 5 + 255) / 256, 256, 0, stream>>>(agg1, W2, h2, N);
    agg2_lsm_kernel<<<(N * 64 + 255) / 256, 256, 0, stream>>>(h2, rowptr, srcs, out, N);
}